// Round 4
// baseline (588.599 us; speedup 1.0000x reference)
//
#include <hip/hip_runtime.h>
#include <hip/hip_bf16.h>
#include <cstring>

using bf16 = __hip_bfloat16;
typedef _Float16 h2v __attribute__((ext_vector_type(2)));
typedef _Float16 h8v __attribute__((ext_vector_type(8)));

#if __has_builtin(__builtin_amdgcn_fdot2)
__device__ __forceinline__ float FDOT2(h2v a, h2v b, float c) {
    return __builtin_amdgcn_fdot2(a, b, c, false);
}
#else
__device__ __forceinline__ float FDOT2(h2v a, h2v b, float c) {
    return c + (float)a.x * (float)b.x + (float)a.y * (float)b.y;
}
#endif

// fast sigmoid/tanh: v_exp_f32 + v_rcp_f32, saturate correctly at +-inf, no NaN.
__device__ __forceinline__ float sigm_f(float x) {
    return __builtin_amdgcn_rcpf(1.f + __expf(-x));
}
__device__ __forceinline__ float tanh_f(float x) {
    return 1.f - 2.f * __builtin_amdgcn_rcpf(1.f + __expf(2.f * x));
}

// ---- problem constants ----
constexpr int NH    = 128;    // hidden
constexpr int G4    = 512;    // 4*H gates
constexpr int TSEQ  = 200;
constexpr int BBATCH= 32;
constexpr int NTGT  = 8;

// ---- subgraph caps (Poisson means: |L1|~64, |S1|~72, |L2|~580, |S2|~650) ----
constexpr int LCAP1 = 1024;
constexpr int S1CAP = LCAP1 + NTGT;
constexpr int LCAP2 = 8192;
constexpr int S2CAP = LCAP2 + S1CAP;

// ---- workspace layout (bytes) ----
constexpr size_t algn(size_t x) { return (x + 255) & ~size_t(255); }
constexpr size_t OFF_GX1  = 0;                                            // 6400*512 f32
constexpr size_t OFF_GX2  = algn(OFF_GX1  + 6400ull * G4 * 4);            // 32*512 f32
constexpr size_t OFF_DEG  = algn(OFF_GX2  + 32ull * G4 * 4);              // N i32
constexpr size_t OFF_DINV = algn(OFF_DEG  + 100000ull * 4);               // (unused, kept)
constexpr size_t OFF_SL1  = algn(OFF_DINV + 100000ull * 4);               // N i32
constexpr size_t OFF_SL2  = algn(OFF_SL1  + 100000ull * 4);               // N i32
constexpr size_t OFF_CNT  = algn(OFF_SL2  + 100000ull * 4);               // 16 i32
constexpr size_t OFF_L1   = algn(OFF_CNT  + 64);                          // LCAP1 int2
constexpr size_t OFF_S1   = algn(OFF_L1   + (size_t)LCAP1 * 8);           // S1CAP i32
constexpr size_t OFF_L2   = algn(OFF_S1   + (size_t)S1CAP * 4);           // LCAP2 int2
constexpr size_t OFF_S2   = algn(OFF_L2   + (size_t)LCAP2 * 8);           // S2CAP i32
constexpr size_t OFF_XW1  = algn(OFF_S2   + (size_t)S2CAP * 4);           // S2CAP*128 f32
constexpr size_t OFF_H1   = algn(OFF_XW1  + (size_t)S2CAP * NH * 4);      // S1CAP*128 f32
constexpr size_t OFF_XW2  = algn(OFF_H1   + (size_t)S1CAP * NH * 4);      // S1CAP*128 f32
constexpr size_t OFF_DVEC = algn(OFF_XW2  + (size_t)S1CAP * NH * 4);      // 1152 f32
constexpr size_t OFF_H1F  = algn(OFF_DVEC + 1152ull * 4);                 // 32*128 f32
constexpr size_t OFF_CACC = algn(OFF_H1F  + 32ull * NH * 4);              // 576 f32
constexpr size_t WS_NEEDED = OFF_CACC + 576ull * 4;

// edge_index may be staged as int64 (reference dtype) or int32. If int64,
// odd int32 words are the (all-zero) high halves. cnt[15] = sniffed flag.
__device__ __forceinline__ int edge_at(const int* ei, int E, int is64, int row, int e) {
    return is64 ? ei[(((size_t)row * E) + e) * 2] : ei[((size_t)row * E) + e];
}

__device__ __forceinline__ float dinv_of(const int* deg, int v) {
    return rsqrtf((float)deg[v] + 1.0f);
}

// ============================ GCN subgraph build ============================
// canary + colacc/h1 zero folded here (R12 folds kept; R13 reverts the
// cooperative/fusion experiments — boundaries proved cheaper than serial
// single-CU fused kernels).
__global__ void k_init(const int* ei, int* deg, int* slot1, int* slot2, int* cnt,
                       float* h1, float* colacc, int n, unsigned int* out, unsigned int canary) {
    int i0 = blockIdx.x * 256 + threadIdx.x;
    int gstride = gridDim.x * 256;
    if (i0 < 14) cnt[i0] = 0;
    if (i0 == 15) cnt[15] = (ei[1] == 0 && ei[3] == 0 && ei[5] == 0 && ei[7] == 0) ? 1 : 0;
    if (i0 == 16) out[0] = canary;      // diagnostic; overwritten by k_head2
    if (i0 < 576) colacc[i0] = 0.f;
    for (int i = i0; i < S1CAP * NH; i += gstride) h1[i] = 0.f;
    for (int i = i0; i < n; i += gstride) { deg[i] = 0; slot1[i] = -1; slot2[i] = -1; }
}

__global__ void k_deg_l1(const int* ei, int E, int* deg, int2* l1, int* cnt) {
    int is64 = cnt[15];
    for (int e = blockIdx.x * 256 + threadIdx.x; e < E; e += gridDim.x * 256) {
        int d = edge_at(ei, E, is64, 1, e);
        if ((unsigned)d < 100000u) atomicAdd(&deg[d], 1);
        if (d <= 7000 && d >= 0 && d % 1000 == 0) {          // d in TARGET
            int s = edge_at(ei, E, is64, 0, e);
            int idx = atomicAdd(&cnt[0], 1);
            if (idx < LCAP1) l1[idx] = make_int2(s, d);
        }
    }
}

// S1 set build + S2 seeding (single block)
__global__ void k_s1(const int2* l1, int* cnt, int* slot1, int* s1list,
                     int* slot2, int* s2list) {
    __shared__ int ns1;
    if (threadIdx.x == 0) ns1 = 0;
    __syncthreads();
    int m = min(cnt[0], LCAP1);
    for (int i = threadIdx.x; i < NTGT + m; i += blockDim.x) {
        int v = (i < NTGT) ? i * 1000 : l1[i - NTGT].x;
        if ((unsigned)v >= 100000u) continue;
        int old = atomicCAS(&slot1[v], -1, -2);
        if (old == -1) {
            int idx = atomicAdd(&ns1, 1);
            if (idx < S1CAP) { s1list[idx] = v; atomicExch(&slot1[v], idx); }
        }
    }
    __syncthreads();
    int n1 = min(ns1, S1CAP);
    if (threadIdx.x == 0) cnt[1] = n1;
    for (int i = threadIdx.x; i < n1; i += blockDim.x) {
        int v = s1list[i];
        int old = atomicCAS(&slot2[v], -1, -2);
        if (old == -1) {
            int idx = atomicAdd(&cnt[2], 1);
            if (idx < S2CAP) { s2list[idx] = v; atomicExch(&slot2[v], idx); }
        }
    }
}

__global__ void k_l2(const int* ei, int E, const int* slot1,
                     int2* l2, int* cnt, int* slot2, int* s2list) {
    int is64 = cnt[15];
    for (int e = blockIdx.x * 256 + threadIdx.x; e < E; e += gridDim.x * 256) {
        int d = edge_at(ei, E, is64, 1, e);
        if ((unsigned)d >= 100000u) continue;
        if (slot1[d] >= 0) {
            int s = edge_at(ei, E, is64, 0, e);
            if ((unsigned)s >= 100000u) continue;
            int idx = atomicAdd(&cnt[3], 1);
            if (idx < LCAP2) l2[idx] = make_int2(s, d);
            int old = atomicCAS(&slot2[s], -1, -2);
            if (old == -1) {
                int j = atomicAdd(&cnt[2], 1);
                if (j < S2CAP) { s2list[j] = s; atomicExch(&slot2[s], j); }
            }
        }
    }
}

// ============================ GCN compute (fp32 inputs) ============================

__global__ void k_xw1(const float* x, const float* W, const int* s2list, const int* cnt, float* xw1) {
    int i = blockIdx.x;
    if (i >= min(cnt[2], S2CAP)) return;
    int node = s2list[i];
    __shared__ float xs[NH];
    int c = threadIdx.x;
    xs[c] = x[(size_t)node * NH + c];
    __syncthreads();
    float acc = 0.f;
    #pragma unroll 8
    for (int k = 0; k < NH; k++) acc += xs[k] * W[(size_t)k * NH + c];
    xw1[(size_t)i * NH + c] = acc;
}

__global__ void k_h1scat(const float* xw1, const int2* l2, const int* cnt,
                         const int* slot1, const int* slot2, const int* deg, float* h1) {
    int e = blockIdx.x;
    if (e >= min(cnt[3], LCAP2)) return;
    int2 sd = l2[e];
    int t1 = slot1[sd.y], s2 = slot2[sd.x];
    if (t1 < 0 || t1 >= S1CAP || s2 < 0 || s2 >= S2CAP) return;
    float w = dinv_of(deg, sd.x) * dinv_of(deg, sd.y);
    atomicAdd(&h1[t1 * NH + threadIdx.x],
              xw1[(size_t)s2 * NH + threadIdx.x] * w);
}

// self-loop base term folded in (h1init dispatch removed):
// xs = relu(h1_scatter + xw1[node]*dinv^2 + b1), then @ W2.
__global__ void k_xw2(const float* h1, const float* xw1, const float* W, const float* b1,
                      const int* cnt, const int* s1list, const int* slot2, const int* deg,
                      float* xw2) {
    int i = blockIdx.x;
    if (i >= min(cnt[1], S1CAP)) return;
    __shared__ float xs[NH];
    int c = threadIdx.x;
    int node = s1list[i];
    int s2i = slot2[node];
    if (s2i < 0 || s2i >= S2CAP) s2i = 0;
    float v = dinv_of(deg, node);
    xs[c] = fmaxf(h1[i * NH + c] + xw1[(size_t)s2i * NH + c] * (v * v) + b1[c], 0.f);
    __syncthreads();
    float acc = 0.f;
    #pragma unroll 8
    for (int k = 0; k < NH; k++) acc += xs[k] * W[(size_t)k * NH + c];
    xw2[(size_t)i * NH + c] = acc;
}

__global__ void k_gout(const float* xw2, const int2* l1, const int* cnt,
                       const int* slot1, const int* deg, const float* b2, float* dvec) {
    int t = blockIdx.x;             // 0..7
    int tgt = t * 1000;
    int c = threadIdx.x;
    float vt = dinv_of(deg, tgt);
    int st = slot1[tgt]; if (st < 0 || st >= S1CAP) st = 0;
    float acc = xw2[(size_t)st * NH + c] * vt * vt;
    int m = min(cnt[0], LCAP1);
    for (int e = 0; e < m; e++) {
        int2 sd = l1[e];
        if (sd.y == tgt) {
            int ss = slot1[sd.x];
            if (ss >= 0 && ss < S1CAP)
                acc += xw2[(size_t)ss * NH + c] * dinv_of(deg, sd.x) * vt;
        }
    }
    acc += b2[c];
    dvec[t * NH + c] = fmaxf(acc, 0.f);
}

// ============================ LSTM (fp32 inputs) ============================

// gx1 = data0_rows @ Wih1^T + bias, LDS-tiled GEMM.
__global__ __launch_bounds__(256) void k_gx1(const float* data0, const float* Wih,
                                             const float* bih, const float* bhh, float* gx) {
    constexpr int LDP = 68;                       // pad 64->68 breaks bank conflicts
    __shared__ float As[64 * LDP];                // rows x k
    __shared__ float Bs[64 * LDP];                // gates x k
    int tid = threadIdx.x;
    int rb = blockIdx.x >> 3;                     // 0..99  row block
    int gb = blockIdx.x & 7;                      // 0..7   gate block
    int r0 = rb * 64, g0 = gb * 64;
    for (int i = tid; i < 64 * 64; i += 256) {
        int rr = i >> 6, k = i & 63;
        int r = r0 + rr, b = r & 31, t = r >> 5;
        As[rr * LDP + k] = data0[((size_t)b * TSEQ + t) * 64 + k];
        Bs[rr * LDP + k] = Wih[(size_t)(g0 + rr) * 64 + k];
    }
    __syncthreads();
    int tr = (tid & 15) * 4;                      // 4 rows
    int tg = (tid >> 4) * 4;                      // 4 gates
    float acc[4][4] = {};
    #pragma unroll
    for (int k4 = 0; k4 < 16; k4++) {
        float4 a0 = *(const float4*)&As[(tr + 0) * LDP + k4 * 4];
        float4 a1 = *(const float4*)&As[(tr + 1) * LDP + k4 * 4];
        float4 a2 = *(const float4*)&As[(tr + 2) * LDP + k4 * 4];
        float4 a3 = *(const float4*)&As[(tr + 3) * LDP + k4 * 4];
        float4 b0 = *(const float4*)&Bs[(tg + 0) * LDP + k4 * 4];
        float4 b1 = *(const float4*)&Bs[(tg + 1) * LDP + k4 * 4];
        float4 b2 = *(const float4*)&Bs[(tg + 2) * LDP + k4 * 4];
        float4 b3 = *(const float4*)&Bs[(tg + 3) * LDP + k4 * 4];
        const float4 av[4] = {a0, a1, a2, a3};
        const float4 bv[4] = {b0, b1, b2, b3};
        #pragma unroll
        for (int i = 0; i < 4; i++)
            #pragma unroll
            for (int j = 0; j < 4; j++)
                acc[i][j] += av[i].x * bv[j].x + av[i].y * bv[j].y
                           + av[i].z * bv[j].z + av[i].w * bv[j].w;
    }
    float bias[4];
    #pragma unroll
    for (int j = 0; j < 4; j++) bias[j] = bih[g0 + tg + j] + bhh[g0 + tg + j];
    #pragma unroll
    for (int i = 0; i < 4; i++) {
        size_t row = (size_t)(r0 + tr + i) * G4 + g0 + tg;
        #pragma unroll
        for (int j = 0; j < 4; j++) gx[row + j] = acc[i][j] + bias[j];
    }
}

// gx2[t][g] = h1f[t][:] . Wih2[g][:] + biases; 256 thr, 2 gates.
__global__ void k_gx2(const float* h1f, const float* Wih,
                      const float* bih, const float* bhh, float* gx) {
    int t = blockIdx.x;
    __shared__ float xs[NH];
    int tid = threadIdx.x;
    int g0 = tid, g1 = tid + 256;
    if (tid < NH) xs[tid] = h1f[t * NH + tid];
    __syncthreads();
    float a0 = bih[g0] + bhh[g0];
    float a1 = bih[g1] + bhh[g1];
    #pragma unroll 4
    for (int k = 0; k < NH; k++) {
        a0 += Wih[(size_t)g0 * NH + k] * xs[k];
        a1 += Wih[(size_t)g1 * NH + k] * xs[k];
    }
    gx[(size_t)t * G4 + g0] = a0;
    gx[(size_t)t * G4 + g1] = a1;
}

// R13 role-merged recurrence: 128 threads = 2 waves; lane l of wave w owns
// unit j = w*64+l and computes ALL FOUR gate rows (i,f,g,o) — weights for the
// 4 rows live in 256 VGPRs (launch_bounds(128,1) -> 1 wave/SIMD, <=512 VGPR).
// Why: the per-step LDS-pipe model (validated by R0=1505 / R1=2172 cyc steps:
// step ~ 12cyc x ds_read_b128-per-CU + ~700 fixed) says the 4-wave role-split
// spent 768 cyc/step broadcasting h; 2 waves spend 384. Also removes both
// permlane crossings from the serial chain (cell update is lane-local now).
template<int T, int NB>
__global__ __launch_bounds__(128, 1) void k_lstm(const float* gx, const float* Whh, float* hfinal) {
    int b = blockIdx.x;
    int tid = threadIdx.x;                        // 0..127
    int j = tid;                                  // hidden unit (2 waves x 64 lanes)
    __shared__ __align__(16) _Float16 hbuf[2][NH];
    h2v w0[NH / 2], w1[NH / 2], w2[NH / 2], w3[NH / 2];
    #pragma unroll
    for (int k = 0; k < NH; k += 4) {
        float4 ai = *(const float4*)&Whh[(size_t)j * NH + k];
        w0[k / 2]     = h2v{(_Float16)ai.x, (_Float16)ai.y};
        w0[k / 2 + 1] = h2v{(_Float16)ai.z, (_Float16)ai.w};
        float4 af = *(const float4*)&Whh[(size_t)(j + NH) * NH + k];
        w1[k / 2]     = h2v{(_Float16)af.x, (_Float16)af.y};
        w1[k / 2 + 1] = h2v{(_Float16)af.z, (_Float16)af.w};
        float4 ag = *(const float4*)&Whh[(size_t)(j + 2 * NH) * NH + k];
        w2[k / 2]     = h2v{(_Float16)ag.x, (_Float16)ag.y};
        w2[k / 2 + 1] = h2v{(_Float16)ag.z, (_Float16)ag.w};
        float4 ao = *(const float4*)&Whh[(size_t)(j + 3 * NH) * NH + k];
        w3[k / 2]     = h2v{(_Float16)ao.x, (_Float16)ao.y};
        w3[k / 2 + 1] = h2v{(_Float16)ao.z, (_Float16)ao.w};
    }
    hbuf[0][tid] = (_Float16)0.f;
    hbuf[1][tid] = (_Float16)0.f;
    float c = 0.f, hout = 0.f;
    const float* g0p = &gx[(size_t)b * G4];
    float nx0 = g0p[j], nx1 = g0p[j + NH], nx2 = g0p[j + 2 * NH], nx3 = g0p[j + 3 * NH];
    __syncthreads();
    for (int t = 0; t < T; t++) {
        const h8v* hv8 = (const h8v*)hbuf[t & 1];           // read prev-state buffer
        float a0 = nx0, a1 = nx1, a2 = nx2, a3 = nx3;
        int tn = (t + 1 < T) ? (t + 1) : t;
        const float* gp = &gx[((size_t)tn * NB + b) * G4];  // prefetch next step
        nx0 = gp[j]; nx1 = gp[j + NH]; nx2 = gp[j + 2 * NH]; nx3 = gp[j + 3 * NH];
        float p0 = 0.f, q0 = 0.f, p1 = 0.f, q1 = 0.f;
        float p2 = 0.f, q2 = 0.f, p3 = 0.f, q3 = 0.f;
        #pragma unroll
        for (int m = 0; m < NH / 8; m++) {                  // 16 b128 broadcast reads
            h8v h8 = hv8[m];
            h2v ha = __builtin_shufflevector(h8, h8, 0, 1);
            h2v hb = __builtin_shufflevector(h8, h8, 2, 3);
            h2v hc = __builtin_shufflevector(h8, h8, 4, 5);
            h2v hd = __builtin_shufflevector(h8, h8, 6, 7);
            p0 = FDOT2(w0[4 * m],     ha, p0);
            q0 = FDOT2(w0[4 * m + 1], hb, q0);
            p0 = FDOT2(w0[4 * m + 2], hc, p0);
            q0 = FDOT2(w0[4 * m + 3], hd, q0);
            p1 = FDOT2(w1[4 * m],     ha, p1);
            q1 = FDOT2(w1[4 * m + 1], hb, q1);
            p1 = FDOT2(w1[4 * m + 2], hc, p1);
            q1 = FDOT2(w1[4 * m + 3], hd, q1);
            p2 = FDOT2(w2[4 * m],     ha, p2);
            q2 = FDOT2(w2[4 * m + 1], hb, q2);
            p2 = FDOT2(w2[4 * m + 2], hc, p2);
            q2 = FDOT2(w2[4 * m + 3], hd, q2);
            p3 = FDOT2(w3[4 * m],     ha, p3);
            q3 = FDOT2(w3[4 * m + 1], hb, q3);
            p3 = FDOT2(w3[4 * m + 2], hc, p3);
            q3 = FDOT2(w3[4 * m + 3], hd, q3);
        }
        float gi = a0 + p0 + q0;
        float gf = a1 + p1 + q1;
        float gg = a2 + p2 + q2;
        float go = a3 + p3 + q3;
        float si = sigm_f(gi);
        float sf = sigm_f(gf);
        float tg = tanh_f(gg);
        float so = sigm_f(go);
        c = sf * c + si * tg;
        hout = so * tanh_f(c);
        hbuf[(t + 1) & 1][j] = (_Float16)hout;              // write other buffer
        __syncthreads();                                    // single 2-wave barrier
    }
    hfinal[(size_t)b * NH + j] = hout;
}

// ============================ head ============================
// pass 1: 72 blocks (9 col-groups x 8 row-groups) x 64 lanes.
__global__ __launch_bounds__(64) void k_head1(const float* dvec, const float* m1w, float* colacc) {
    int rg = blockIdx.x & 7;           // 8 row groups x 144 rows
    int cg = blockIdx.x >> 3;          // 9 col groups x 64 cols
    int col = cg * 64 + threadIdx.x;
    int r0 = rg * 144;
    float acc = 0.f;
    #pragma unroll 4
    for (int i = r0; i < r0 + 144; i++)
        acc += dvec[i] * m1w[(size_t)i * 576 + col];
    atomicAdd(&colacc[col], acc);
}

// pass 2: out = sum_col (colacc+m1b)*m2w + m2b; dual-dtype store.
__global__ __launch_bounds__(256) void k_head2(const float* colacc, const float* m1b,
                                               const float* m2w, const float* m2b,
                                               unsigned int* out) {
    __shared__ float wr[4];
    int j = threadIdx.x;
    float sum = 0.f;
    for (int col = j; col < 576; col += 256)
        sum += (colacc[col] + m1b[col]) * m2w[col];
    #pragma unroll
    for (int off = 32; off > 0; off >>= 1) sum += __shfl_down(sum, off, 64);
    if ((j & 63) == 0) wr[j >> 6] = sum;
    __syncthreads();
    if (j == 0) {
        float s = wr[0] + wr[1] + wr[2] + wr[3] + m2b[0];
        bf16 hb = __float2bfloat16(s);
        unsigned short u;
        memcpy(&u, &hb, 2);
        out[0] = ((unsigned int)u << 16) | u;
    }
}

// ============================ launcher ============================

extern "C" void kernel_launch(void* const* d_in, const int* in_sizes, int n_in,
                              void* d_out, int out_size, void* d_ws, size_t ws_size,
                              hipStream_t stream) {
    const float* data0 = (const float*)d_in[0];
    const float* data1 = (const float*)d_in[1];
    const int*   ei    = (const int*)d_in[2];
    const float* W1    = (const float*)d_in[3];
    const float* b1    = (const float*)d_in[4];
    const float* W2    = (const float*)d_in[5];
    const float* b2    = (const float*)d_in[6];
    const float* Wih1  = (const float*)d_in[7];
    const float* Whh1  = (const float*)d_in[8];
    const float* bih1  = (const float*)d_in[9];
    const float* bhh1  = (const float*)d_in[10];
    const float* Wih2  = (const float*)d_in[11];
    const float* Whh2  = (const float*)d_in[12];
    const float* bih2  = (const float*)d_in[13];
    const float* bhh2  = (const float*)d_in[14];
    const float* m1w   = (const float*)d_in[15];
    const float* m1b   = (const float*)d_in[16];
    const float* m2w   = (const float*)d_in[17];
    const float* m2b   = (const float*)d_in[18];

    const int n = in_sizes[1] / NH;       // 100000
    const int E = in_sizes[2] / 2;        // 800000 (elements; int width sniffed on device)

    char* ws = (char*)d_ws;
    float* gx1   = (float*)(ws + OFF_GX1);
    float* gx2   = (float*)(ws + OFF_GX2);
    int*   deg   = (int*)  (ws + OFF_DEG);
    int*   slot1 = (int*)  (ws + OFF_SL1);
    int*   slot2 = (int*)  (ws + OFF_SL2);
    int*   cnt   = (int*)  (ws + OFF_CNT);
    int2*  l1    = (int2*) (ws + OFF_L1);
    int*   s1l   = (int*)  (ws + OFF_S1);
    int2*  l2    = (int2*) (ws + OFF_L2);
    int*   s2l   = (int*)  (ws + OFF_S2);
    float* xw1   = (float*)(ws + OFF_XW1);
    float* h1    = (float*)(ws + OFF_H1);
    float* xw2   = (float*)(ws + OFF_XW2);
    float* dvec  = (float*)(ws + OFF_DVEC);
    float* h1f   = (float*)(ws + OFF_H1F);
    float* cacc  = (float*)(ws + OFF_CACC);

    // diagnostic canary bits (written by k_init, overwritten by k_head2)
    float v = 1.0f + (ws_size < WS_NEEDED ? 1.0f : 0.0f) + (n_in != 19 ? 2.0f : 0.0f);
    unsigned int fb; memcpy(&fb, &v, 4);
    unsigned int hi = fb >> 16;
    unsigned int canary_bits = (hi << 16) | hi;

    int nb = (n + 255) / 256;
    int eb = (E + 255) / 256;

    // subgraph build
    k_init   <<<nb, 256, 0, stream>>>(ei, deg, slot1, slot2, cnt, h1, cacc, n,
                                      (unsigned int*)d_out, canary_bits);
    k_deg_l1 <<<eb, 256, 0, stream>>>(ei, E, deg, l1, cnt);
    k_s1     <<<1, 256, 0, stream>>>(l1, cnt, slot1, s1l, slot2, s2l);
    k_l2     <<<eb, 256, 0, stream>>>(ei, E, slot1, l2, cnt, slot2, s2l);
    // GCN compute on active subgraph
    k_xw1    <<<S2CAP, NH, 0, stream>>>(data1, W1, s2l, cnt, xw1);
    k_h1scat <<<LCAP2, NH, 0, stream>>>(xw1, l2, cnt, slot1, slot2, deg, h1);
    k_xw2    <<<S1CAP, NH, 0, stream>>>(h1, xw1, W2, b1, cnt, s1l, slot2, deg, xw2);
    k_gout   <<<NTGT, NH, 0, stream>>>(xw2, l1, cnt, slot1, deg, b2, dvec);
    // LSTM path
    k_gx1    <<<800, 256, 0, stream>>>(data0, Wih1, bih1, bhh1, gx1);
    k_lstm<TSEQ, BBATCH><<<BBATCH, 128, 0, stream>>>(gx1, Whh1, h1f);
    k_gx2    <<<BBATCH, 256, 0, stream>>>(h1f, Wih2, bih2, bhh2, gx2);
    k_lstm<BBATCH, 1>  <<<1, 128, 0, stream>>>(gx2, Whh2, dvec + 1024);
    // head
    k_head1  <<<72, 64, 0, stream>>>(dvec, m1w, cacc);
    k_head2  <<<1, 256, 0, stream>>>(cacc, m1b, m2w, m2b, (unsigned int*)d_out);
    (void)out_size;
}

// Round 5
// 421.781 us; speedup vs baseline: 1.3955x; 1.3955x over previous
//
#include <hip/hip_runtime.h>
#include <hip/hip_bf16.h>
#include <cstring>

using bf16 = __hip_bfloat16;
typedef _Float16 h2v __attribute__((ext_vector_type(2)));
typedef _Float16 h8v __attribute__((ext_vector_type(8)));

#if __has_builtin(__builtin_amdgcn_fdot2)
__device__ __forceinline__ float FDOT2(h2v a, h2v b, float c) {
    return __builtin_amdgcn_fdot2(a, b, c, false);
}
#else
__device__ __forceinline__ float FDOT2(h2v a, h2v b, float c) {
    return c + (float)a.x * (float)b.x + (float)a.y * (float)b.y;
}
#endif

// fast sigmoid/tanh: v_exp_f32 + v_rcp_f32, saturate correctly at +-inf, no NaN.
__device__ __forceinline__ float sigm_f(float x) {
    return __builtin_amdgcn_rcpf(1.f + __expf(-x));
}
__device__ __forceinline__ float tanh_f(float x) {
    return 1.f - 2.f * __builtin_amdgcn_rcpf(1.f + __expf(2.f * x));
}

// lane l (l<32) gets value of lane l+32. VALU permlane32_swap (gfx950) instead
// of ds_bpermute: keeps the gate crossing off the LDS pipe.
__device__ __forceinline__ float xor32_get(float x) {
#if __has_builtin(__builtin_amdgcn_permlane32_swap)
    typedef unsigned uv2 __attribute__((ext_vector_type(2)));
    union { float f; unsigned u; } cv; cv.f = x;
    uv2 r = __builtin_amdgcn_permlane32_swap(cv.u, cv.u, false, false);
    union { unsigned u; float f; } rv; rv.u = r[1];
    return rv.f;
#else
    return __shfl_xor(x, 32);
#endif
}

// ---- problem constants ----
constexpr int NH    = 128;    // hidden
constexpr int G4    = 512;    // 4*H gates
constexpr int TSEQ  = 200;
constexpr int BBATCH= 32;
constexpr int NTGT  = 8;

// ---- subgraph caps (Poisson means: |L1|~64, |S1|~72, |L2|~580, |S2|~650) ----
constexpr int LCAP1 = 1024;
constexpr int S1CAP = LCAP1 + NTGT;
constexpr int LCAP2 = 8192;
constexpr int S2CAP = LCAP2 + S1CAP;

// ---- workspace layout (bytes) ----
constexpr size_t algn(size_t x) { return (x + 255) & ~size_t(255); }
constexpr size_t OFF_GX1  = 0;                                            // 6400*512 f32
constexpr size_t OFF_GX2  = algn(OFF_GX1  + 6400ull * G4 * 4);            // 32*512 f32
constexpr size_t OFF_DEG  = algn(OFF_GX2  + 32ull * G4 * 4);              // N i32
constexpr size_t OFF_DINV = algn(OFF_DEG  + 100000ull * 4);               // hw: 1153 f32
constexpr size_t OFF_SL1  = algn(OFF_DINV + 100000ull * 4);               // N i32
constexpr size_t OFF_SL2  = algn(OFF_SL1  + 100000ull * 4);               // N i32
constexpr size_t OFF_CNT  = algn(OFF_SL2  + 100000ull * 4);               // 16 i32
constexpr size_t OFF_L1   = algn(OFF_CNT  + 64);                          // LCAP1 int2
constexpr size_t OFF_S1   = algn(OFF_L1   + (size_t)LCAP1 * 8);           // S1CAP i32
constexpr size_t OFF_L2   = algn(OFF_S1   + (size_t)S1CAP * 4);           // LCAP2 int2
constexpr size_t OFF_S2   = algn(OFF_L2   + (size_t)LCAP2 * 8);           // S2CAP i32
constexpr size_t OFF_XW1  = algn(OFF_S2   + (size_t)S2CAP * 4);           // S2CAP*128 f32
constexpr size_t OFF_H1   = algn(OFF_XW1  + (size_t)S2CAP * NH * 4);      // S1CAP*128 f32
constexpr size_t OFF_XW2  = algn(OFF_H1   + (size_t)S1CAP * NH * 4);      // S1CAP*128 f32
constexpr size_t OFF_DVEC = algn(OFF_XW2  + (size_t)S1CAP * NH * 4);      // 1152 f32
constexpr size_t OFF_H1F  = algn(OFF_DVEC + 1152ull * 4);                 // 32*128 f32 (unused, kept)
constexpr size_t OFF_CACC = algn(OFF_H1F  + 32ull * NH * 4);              // 576 f32 (unused, kept)
constexpr size_t WS_NEEDED = OFF_CACC + 576ull * 4;

// edge_index may be staged as int64 (reference dtype) or int32. If int64,
// odd int32 words are the (all-zero) high halves. cnt[15] = sniffed flag.
__device__ __forceinline__ int edge_at(const int* ei, int E, int is64, int row, int e) {
    return is64 ? ei[(((size_t)row * E) + e) * 2] : ei[((size_t)row * E) + e];
}

__device__ __forceinline__ float dinv_of(const int* deg, int v) {
    return rsqrtf((float)deg[v] + 1.0f);
}

// ============================ GCN subgraph build ============================
__global__ void k_init(const int* ei, int* deg, int* slot1, int* slot2, int* cnt,
                       float* h1, int n, unsigned int* out, unsigned int canary) {
    int i0 = blockIdx.x * 256 + threadIdx.x;
    int gstride = gridDim.x * 256;
    if (i0 < 14) cnt[i0] = 0;
    if (i0 == 15) cnt[15] = (ei[1] == 0 && ei[3] == 0 && ei[5] == 0 && ei[7] == 0) ? 1 : 0;
    if (i0 == 16) out[0] = canary;      // diagnostic; overwritten by k_lstm2h
    for (int i = i0; i < S1CAP * NH; i += gstride) h1[i] = 0.f;
    for (int i = i0; i < n; i += gstride) { deg[i] = 0; slot1[i] = -1; slot2[i] = -1; }
}

__global__ void k_deg_l1(const int* ei, int E, int* deg, int2* l1, int* cnt) {
    int is64 = cnt[15];
    for (int e = blockIdx.x * 256 + threadIdx.x; e < E; e += gridDim.x * 256) {
        int d = edge_at(ei, E, is64, 1, e);
        if ((unsigned)d < 100000u) atomicAdd(&deg[d], 1);
        if (d <= 7000 && d >= 0 && d % 1000 == 0) {          // d in TARGET
            int s = edge_at(ei, E, is64, 0, e);
            int idx = atomicAdd(&cnt[0], 1);
            if (idx < LCAP1) l1[idx] = make_int2(s, d);
        }
    }
}

// S1 set build + S2 seeding (single block)
__global__ void k_s1(const int2* l1, int* cnt, int* slot1, int* s1list,
                     int* slot2, int* s2list) {
    __shared__ int ns1;
    if (threadIdx.x == 0) ns1 = 0;
    __syncthreads();
    int m = min(cnt[0], LCAP1);
    for (int i = threadIdx.x; i < NTGT + m; i += blockDim.x) {
        int v = (i < NTGT) ? i * 1000 : l1[i - NTGT].x;
        if ((unsigned)v >= 100000u) continue;
        int old = atomicCAS(&slot1[v], -1, -2);
        if (old == -1) {
            int idx = atomicAdd(&ns1, 1);
            if (idx < S1CAP) { s1list[idx] = v; atomicExch(&slot1[v], idx); }
        }
    }
    __syncthreads();
    int n1 = min(ns1, S1CAP);
    if (threadIdx.x == 0) cnt[1] = n1;
    for (int i = threadIdx.x; i < n1; i += blockDim.x) {
        int v = s1list[i];
        int old = atomicCAS(&slot2[v], -1, -2);
        if (old == -1) {
            int idx = atomicAdd(&cnt[2], 1);
            if (idx < S2CAP) { s2list[idx] = v; atomicExch(&slot2[v], idx); }
        }
    }
}

__global__ void k_l2(const int* ei, int E, const int* slot1,
                     int2* l2, int* cnt, int* slot2, int* s2list) {
    int is64 = cnt[15];
    for (int e = blockIdx.x * 256 + threadIdx.x; e < E; e += gridDim.x * 256) {
        int d = edge_at(ei, E, is64, 1, e);
        if ((unsigned)d >= 100000u) continue;
        if (slot1[d] >= 0) {
            int s = edge_at(ei, E, is64, 0, e);
            if ((unsigned)s >= 100000u) continue;
            int idx = atomicAdd(&cnt[3], 1);
            if (idx < LCAP2) l2[idx] = make_int2(s, d);
            int old = atomicCAS(&slot2[s], -1, -2);
            if (old == -1) {
                int j = atomicAdd(&cnt[2], 1);
                if (j < S2CAP) { s2list[j] = s; atomicExch(&slot2[s], j); }
            }
        }
    }
}

// ============================ GCN compute (fp32 inputs) ============================

__global__ void k_xw1(const float* x, const float* W, const int* s2list, const int* cnt, float* xw1) {
    int i = blockIdx.x;
    if (i >= min(cnt[2], S2CAP)) return;
    int node = s2list[i];
    __shared__ float xs[NH];
    int c = threadIdx.x;
    xs[c] = x[(size_t)node * NH + c];
    __syncthreads();
    float acc = 0.f;
    #pragma unroll 8
    for (int k = 0; k < NH; k++) acc += xs[k] * W[(size_t)k * NH + c];
    xw1[(size_t)i * NH + c] = acc;
}

__global__ void k_h1scat(const float* xw1, const int2* l2, const int* cnt,
                         const int* slot1, const int* slot2, const int* deg, float* h1) {
    int e = blockIdx.x;
    if (e >= min(cnt[3], LCAP2)) return;
    int2 sd = l2[e];
    int t1 = slot1[sd.y], s2 = slot2[sd.x];
    if (t1 < 0 || t1 >= S1CAP || s2 < 0 || s2 >= S2CAP) return;
    float w = dinv_of(deg, sd.x) * dinv_of(deg, sd.y);
    atomicAdd(&h1[t1 * NH + threadIdx.x],
              xw1[(size_t)s2 * NH + threadIdx.x] * w);
}

// self-loop base term folded in: xs = relu(h1_scatter + xw1[node]*dinv^2 + b1), then @ W2.
__global__ void k_xw2(const float* h1, const float* xw1, const float* W, const float* b1,
                      const int* cnt, const int* s1list, const int* slot2, const int* deg,
                      float* xw2) {
    int i = blockIdx.x;
    if (i >= min(cnt[1], S1CAP)) return;
    __shared__ float xs[NH];
    int c = threadIdx.x;
    int node = s1list[i];
    int s2i = slot2[node];
    if (s2i < 0 || s2i >= S2CAP) s2i = 0;
    float v = dinv_of(deg, node);
    xs[c] = fmaxf(h1[i * NH + c] + xw1[(size_t)s2i * NH + c] * (v * v) + b1[c], 0.f);
    __syncthreads();
    float acc = 0.f;
    #pragma unroll 8
    for (int k = 0; k < NH; k++) acc += xs[k] * W[(size_t)k * NH + c];
    xw2[(size_t)i * NH + c] = acc;
}

__global__ void k_gout(const float* xw2, const int2* l1, const int* cnt,
                       const int* slot1, const int* deg, const float* b2, float* dvec) {
    int t = blockIdx.x;             // 0..7
    int tgt = t * 1000;
    int c = threadIdx.x;
    float vt = dinv_of(deg, tgt);
    int st = slot1[tgt]; if (st < 0 || st >= S1CAP) st = 0;
    float acc = xw2[(size_t)st * NH + c] * vt * vt;
    int m = min(cnt[0], LCAP1);
    for (int e = 0; e < m; e++) {
        int2 sd = l1[e];
        if (sd.y == tgt) {
            int ss = slot1[sd.x];
            if (ss >= 0 && ss < S1CAP)
                acc += xw2[(size_t)ss * NH + c] * dinv_of(deg, sd.x) * vt;
        }
    }
    acc += b2[c];
    dvec[t * NH + c] = fmaxf(acc, 0.f);
}

// ============================ LSTM (fp32 inputs) ============================

// gx1 = data0_rows @ Wih1^T + bias, LDS-tiled GEMM. Blocks >= 800 instead
// compute the head weight-collapse hw = m1w@m2w (1152 f32) + hbias —
// independent weight-only work piggybacked on this dispatch (proven R3-ok).
__global__ __launch_bounds__(256) void k_gx1hw(const float* data0, const float* Wih,
                                               const float* bih, const float* bhh, float* gx,
                                               const float* m1w, const float* m1b,
                                               const float* m2w, const float* m2b, float* hw) {
    int tid = threadIdx.x;
    if (blockIdx.x >= 800) {
        int hb = blockIdx.x - 800;                // 0..18
        int wv = tid >> 6, ln = tid & 63;
        if (hb < 18) {
            #pragma unroll 4
            for (int rr = 0; rr < 16; rr++) {
                int row = hb * 64 + wv * 16 + rr;
                float s = 0.f;
                #pragma unroll
                for (int j = ln; j < 576; j += 64) s += m1w[(size_t)row * 576 + j] * m2w[j];
                #pragma unroll
                for (int off = 32; off > 0; off >>= 1) s += __shfl_down(s, off, 64);
                if (ln == 0) hw[row] = s;
            }
        } else if (wv == 0) {                     // hbias = m1b@m2w + m2b
            float s = 0.f;
            for (int j = ln; j < 576; j += 64) s += m1b[j] * m2w[j];
            #pragma unroll
            for (int off = 32; off > 0; off >>= 1) s += __shfl_down(s, off, 64);
            if (ln == 0) hw[1152] = s + m2b[0];
        }
        return;
    }
    constexpr int LDP = 68;                       // pad 64->68 breaks bank conflicts
    __shared__ float As[64 * LDP];                // rows x k
    __shared__ float Bs[64 * LDP];                // gates x k
    int rb = blockIdx.x >> 3;                     // 0..99  row block
    int gb = blockIdx.x & 7;                      // 0..7   gate block
    int r0 = rb * 64, g0 = gb * 64;
    for (int i = tid; i < 64 * 64; i += 256) {
        int rr = i >> 6, k = i & 63;
        int r = r0 + rr, b = r & 31, t = r >> 5;
        As[rr * LDP + k] = data0[((size_t)b * TSEQ + t) * 64 + k];
        Bs[rr * LDP + k] = Wih[(size_t)(g0 + rr) * 64 + k];
    }
    __syncthreads();
    int tr = (tid & 15) * 4;                      // 4 rows
    int tg = (tid >> 4) * 4;                      // 4 gates
    float acc[4][4] = {};
    #pragma unroll
    for (int k4 = 0; k4 < 16; k4++) {
        float4 a0 = *(const float4*)&As[(tr + 0) * LDP + k4 * 4];
        float4 a1 = *(const float4*)&As[(tr + 1) * LDP + k4 * 4];
        float4 a2 = *(const float4*)&As[(tr + 2) * LDP + k4 * 4];
        float4 a3 = *(const float4*)&As[(tr + 3) * LDP + k4 * 4];
        float4 b0 = *(const float4*)&Bs[(tg + 0) * LDP + k4 * 4];
        float4 b1 = *(const float4*)&Bs[(tg + 1) * LDP + k4 * 4];
        float4 b2 = *(const float4*)&Bs[(tg + 2) * LDP + k4 * 4];
        float4 b3 = *(const float4*)&Bs[(tg + 3) * LDP + k4 * 4];
        const float4 av[4] = {a0, a1, a2, a3};
        const float4 bv[4] = {b0, b1, b2, b3};
        #pragma unroll
        for (int i = 0; i < 4; i++)
            #pragma unroll
            for (int j = 0; j < 4; j++)
                acc[i][j] += av[i].x * bv[j].x + av[i].y * bv[j].y
                           + av[i].z * bv[j].z + av[i].w * bv[j].w;
    }
    float bias[4];
    #pragma unroll
    for (int j = 0; j < 4; j++) bias[j] = bih[g0 + tg + j] + bhh[g0 + tg + j];
    #pragma unroll
    for (int i = 0; i < 4; i++) {
        size_t row = (size_t)(r0 + tr + i) * G4 + g0 + tg;
        #pragma unroll
        for (int j = 0; j < 4; j++) gx[row + j] = acc[i][j] + bias[j];
    }
}

// Proven role-split recurrence (R0/R3, 122.7us, 132 VGPR no spill; R4 lesson:
// >128 h2v weight regs/lane spills to scratch — never role-merge 4 rows).
// Epilogue fold: block b computes its own gx2 row (the old k_gx2 dispatch):
// final h shared as f32 via LDS, 2 gates/thread, divergent-but-L2-hit Wih2 rows.
template<int T, int NB>
__global__ __launch_bounds__(256, 1) void k_lstm1g(const float* gx, const float* Whh,
                                                   const float* Wih2, const float* bih2,
                                                   const float* bhh2, float* gx2) {
    int b = blockIdx.x;
    int tid = threadIdx.x;
    int w = tid >> 6, l = tid & 63;
    int j = w * 32 + (l & 31);                    // hidden unit
    int role = l >> 5;                            // 0: i,g   1: f,o
    int r0 = role ? (j + NH) : j;                 // f-row : i-row
    int r1 = role ? (j + 3 * NH) : (j + 2 * NH);  // o-row : g-row
    __shared__ __align__(16) _Float16 hbuf[2][NH];
    __shared__ float hfin[NH];
    h2v w0[NH / 2], w1[NH / 2];
    #pragma unroll
    for (int k = 0; k < NH; k += 4) {
        float4 a = *(const float4*)&Whh[(size_t)r0 * NH + k];
        w0[k / 2]     = h2v{(_Float16)a.x, (_Float16)a.y};
        w0[k / 2 + 1] = h2v{(_Float16)a.z, (_Float16)a.w};
        float4 c4 = *(const float4*)&Whh[(size_t)r1 * NH + k];
        w1[k / 2]     = h2v{(_Float16)c4.x, (_Float16)c4.y};
        w1[k / 2 + 1] = h2v{(_Float16)c4.z, (_Float16)c4.w};
    }
    if (tid < NH) { hbuf[0][tid] = (_Float16)0.f; hbuf[1][tid] = (_Float16)0.f; }
    float c = 0.f, hout = 0.f;
    float nx0 = gx[((size_t)0 * NB + b) * G4 + r0];
    float nx1 = gx[((size_t)0 * NB + b) * G4 + r1];
    __syncthreads();
    for (int t = 0; t < T; t++) {
        const h8v* hv8 = (const h8v*)hbuf[t & 1];           // read prev-state buffer
        float a0 = nx0, a1 = nx1;
        int tn = (t + 1 < T) ? (t + 1) : t;
        nx0 = gx[((size_t)tn * NB + b) * G4 + r0];          // prefetch next step
        nx1 = gx[((size_t)tn * NB + b) * G4 + r1];
        float p0 = 0.f, q0 = 0.f, p1 = 0.f, q1 = 0.f;
        #pragma unroll
        for (int m = 0; m < NH / 8; m++) {                  // 16 b128 broadcast reads
            h8v h8 = hv8[m];
            h2v ha = __builtin_shufflevector(h8, h8, 0, 1);
            h2v hb = __builtin_shufflevector(h8, h8, 2, 3);
            h2v hc = __builtin_shufflevector(h8, h8, 4, 5);
            h2v hd = __builtin_shufflevector(h8, h8, 6, 7);
            p0 = FDOT2(w0[4 * m],     ha, p0);
            q0 = FDOT2(w0[4 * m + 1], hb, q0);
            p0 = FDOT2(w0[4 * m + 2], hc, p0);
            q0 = FDOT2(w0[4 * m + 3], hd, q0);
            p1 = FDOT2(w1[4 * m],     ha, p1);
            q1 = FDOT2(w1[4 * m + 1], hb, q1);
            p1 = FDOT2(w1[4 * m + 2], hc, p1);
            q1 = FDOT2(w1[4 * m + 3], hd, q1);
        }
        float ga = a0 + p0 + q0;                            // i-pre or f-pre
        float gb = a1 + p1 + q1;                            // g-pre or o-pre
        float s  = sigm_f(ga);                              // sigm(i) | sigm(f)
        float tg = role ? sigm_f(gb) : tanh_f(gb);          // tanh(g) | sigm(o)
        float u  = s * tg;                                  // role0: sigm(i)*tanh(g)
        float fv = xor32_get(s);                            // role0 gets sigm(f)
        float ov = xor32_get(tg);                           // role0 gets sigm(o)
        if (role == 0) {
            c = fv * c + u;
            hout = ov * tanh_f(c);
            hbuf[(t + 1) & 1][j] = (_Float16)hout;          // write other buffer
        }
        __syncthreads();                                    // single barrier/step
    }
    if (role == 0) hfin[j] = hout;                          // exact f32 h for gx2
    __syncthreads();
    // ---- folded k_gx2: gx2[b][g] = hfin . Wih2[g] + biases (2 gates/thread) ----
    int g0 = tid, g1 = tid + 256;
    float a0 = bih2[g0] + bhh2[g0];
    float a1 = bih2[g1] + bhh2[g1];
    #pragma unroll 4
    for (int k = 0; k < NH; k++) {
        float hk = hfin[k];
        a0 += Wih2[(size_t)g0 * NH + k] * hk;
        a1 += Wih2[(size_t)g1 * NH + k] * hk;
    }
    gx2[(size_t)b * G4 + g0] = a0;
    gx2[(size_t)b * G4 + g1] = a1;
}

// lstm2 (T=32, NB=1, 1 block) + folded head epilogue:
// out = dvec[0:1024].hw[0:1024] + h2.hw[1024:1152] + hw[1152]  (bf16 dual store)
__global__ __launch_bounds__(256, 1) void k_lstm2h(const float* gx, const float* Whh,
                                                   const float* dvec, const float* hw,
                                                   unsigned int* out) {
    constexpr int T = BBATCH;                     // 32 steps
    int tid = threadIdx.x;
    int w = tid >> 6, l = tid & 63;
    int j = w * 32 + (l & 31);
    int role = l >> 5;
    int r0 = role ? (j + NH) : j;
    int r1 = role ? (j + 3 * NH) : (j + 2 * NH);
    __shared__ __align__(16) _Float16 hbuf[2][NH];
    __shared__ float harr[NH];
    __shared__ float red[4];
    h2v w0[NH / 2], w1[NH / 2];
    #pragma unroll
    for (int k = 0; k < NH; k += 4) {
        float4 a = *(const float4*)&Whh[(size_t)r0 * NH + k];
        w0[k / 2]     = h2v{(_Float16)a.x, (_Float16)a.y};
        w0[k / 2 + 1] = h2v{(_Float16)a.z, (_Float16)a.w};
        float4 c4 = *(const float4*)&Whh[(size_t)r1 * NH + k];
        w1[k / 2]     = h2v{(_Float16)c4.x, (_Float16)c4.y};
        w1[k / 2 + 1] = h2v{(_Float16)c4.z, (_Float16)c4.w};
    }
    if (tid < NH) { hbuf[0][tid] = (_Float16)0.f; hbuf[1][tid] = (_Float16)0.f; }
    float c = 0.f, hout = 0.f;
    float nx0 = gx[r0];
    float nx1 = gx[r1];
    __syncthreads();
    for (int t = 0; t < T; t++) {
        const h8v* hv8 = (const h8v*)hbuf[t & 1];
        float a0 = nx0, a1 = nx1;
        int tn = (t + 1 < T) ? (t + 1) : t;
        nx0 = gx[(size_t)tn * G4 + r0];
        nx1 = gx[(size_t)tn * G4 + r1];
        float p0 = 0.f, q0 = 0.f, p1 = 0.f, q1 = 0.f;
        #pragma unroll
        for (int m = 0; m < NH / 8; m++) {
            h8v h8 = hv8[m];
            h2v ha = __builtin_shufflevector(h8, h8, 0, 1);
            h2v hb = __builtin_shufflevector(h8, h8, 2, 3);
            h2v hc = __builtin_shufflevector(h8, h8, 4, 5);
            h2v hd = __builtin_shufflevector(h8, h8, 6, 7);
            p0 = FDOT2(w0[4 * m],     ha, p0);
            q0 = FDOT2(w0[4 * m + 1], hb, q0);
            p0 = FDOT2(w0[4 * m + 2], hc, p0);
            q0 = FDOT2(w0[4 * m + 3], hd, q0);
            p1 = FDOT2(w1[4 * m],     ha, p1);
            q1 = FDOT2(w1[4 * m + 1], hb, q1);
            p1 = FDOT2(w1[4 * m + 2], hc, p1);
            q1 = FDOT2(w1[4 * m + 3], hd, q1);
        }
        float ga = a0 + p0 + q0;
        float gb = a1 + p1 + q1;
        float s  = sigm_f(ga);
        float tg = role ? sigm_f(gb) : tanh_f(gb);
        float u  = s * tg;
        float fv = xor32_get(s);
        float ov = xor32_get(tg);
        if (role == 0) {
            c = fv * c + u;
            hout = ov * tanh_f(c);
            hbuf[(t + 1) & 1][j] = (_Float16)hout;
        }
        __syncthreads();
    }
    if (role == 0) harr[j] = hout;
    __syncthreads();
    // ---- folded head: final 1152-dot against collapsed weights hw ----
    float s = 0.f;
    for (int i = tid; i < 1024; i += 256) s += dvec[i] * hw[i];
    if (tid < NH) s += harr[tid] * hw[1024 + tid];
    #pragma unroll
    for (int off = 32; off > 0; off >>= 1) s += __shfl_down(s, off, 64);
    if ((tid & 63) == 0) red[tid >> 6] = s;
    __syncthreads();
    if (tid == 0) {
        float tot = red[0] + red[1] + red[2] + red[3] + hw[1152];
        bf16 hb = __float2bfloat16(tot);
        unsigned short u;
        memcpy(&u, &hb, 2);
        out[0] = ((unsigned int)u << 16) | u;
    }
}

// ============================ launcher ============================

extern "C" void kernel_launch(void* const* d_in, const int* in_sizes, int n_in,
                              void* d_out, int out_size, void* d_ws, size_t ws_size,
                              hipStream_t stream) {
    const float* data0 = (const float*)d_in[0];
    const float* data1 = (const float*)d_in[1];
    const int*   ei    = (const int*)d_in[2];
    const float* W1    = (const float*)d_in[3];
    const float* b1    = (const float*)d_in[4];
    const float* W2    = (const float*)d_in[5];
    const float* b2    = (const float*)d_in[6];
    const float* Wih1  = (const float*)d_in[7];
    const float* Whh1  = (const float*)d_in[8];
    const float* bih1  = (const float*)d_in[9];
    const float* bhh1  = (const float*)d_in[10];
    const float* Wih2  = (const float*)d_in[11];
    const float* Whh2  = (const float*)d_in[12];
    const float* bih2  = (const float*)d_in[13];
    const float* bhh2  = (const float*)d_in[14];
    const float* m1w   = (const float*)d_in[15];
    const float* m1b   = (const float*)d_in[16];
    const float* m2w   = (const float*)d_in[17];
    const float* m2b   = (const float*)d_in[18];

    const int n = in_sizes[1] / NH;       // 100000
    const int E = in_sizes[2] / 2;        // 800000 (elements; int width sniffed on device)

    char* ws = (char*)d_ws;
    float* gx1   = (float*)(ws + OFF_GX1);
    float* gx2   = (float*)(ws + OFF_GX2);
    int*   deg   = (int*)  (ws + OFF_DEG);
    float* hw    = (float*)(ws + OFF_DINV);   // 1153 f32, reuses dead region
    int*   slot1 = (int*)  (ws + OFF_SL1);
    int*   slot2 = (int*)  (ws + OFF_SL2);
    int*   cnt   = (int*)  (ws + OFF_CNT);
    int2*  l1    = (int2*) (ws + OFF_L1);
    int*   s1l   = (int*)  (ws + OFF_S1);
    int2*  l2    = (int2*) (ws + OFF_L2);
    int*   s2l   = (int*)  (ws + OFF_S2);
    float* xw1   = (float*)(ws + OFF_XW1);
    float* h1    = (float*)(ws + OFF_H1);
    float* xw2   = (float*)(ws + OFF_XW2);
    float* dvec  = (float*)(ws + OFF_DVEC);

    // diagnostic canary bits (written by k_init, overwritten by k_lstm2h)
    float v = 1.0f + (ws_size < WS_NEEDED ? 1.0f : 0.0f) + (n_in != 19 ? 2.0f : 0.0f);
    unsigned int fb; memcpy(&fb, &v, 4);
    unsigned int hi = fb >> 16;
    unsigned int canary_bits = (hi << 16) | hi;

    int nb = (n + 255) / 256;
    int eb = (E + 255) / 256;

    // subgraph build
    k_init   <<<nb, 256, 0, stream>>>(ei, deg, slot1, slot2, cnt, h1, n,
                                      (unsigned int*)d_out, canary_bits);
    k_deg_l1 <<<eb, 256, 0, stream>>>(ei, E, deg, l1, cnt);
    k_s1     <<<1, 256, 0, stream>>>(l1, cnt, slot1, s1l, slot2, s2l);
    k_l2     <<<eb, 256, 0, stream>>>(ei, E, slot1, l2, cnt, slot2, s2l);
    // GCN compute on active subgraph
    k_xw1    <<<S2CAP, NH, 0, stream>>>(data1, W1, s2l, cnt, xw1);
    k_h1scat <<<LCAP2, NH, 0, stream>>>(xw1, l2, cnt, slot1, slot2, deg, h1);
    k_xw2    <<<S1CAP, NH, 0, stream>>>(h1, xw1, W2, b1, cnt, s1l, slot2, deg, xw2);
    k_gout   <<<NTGT, NH, 0, stream>>>(xw2, l1, cnt, slot1, deg, b2, dvec);
    // LSTM path (+ head weight-collapse piggybacked on gx1's dispatch)
    k_gx1hw  <<<819, 256, 0, stream>>>(data0, Wih1, bih1, bhh1, gx1,
                                       m1w, m1b, m2w, m2b, hw);
    k_lstm1g<TSEQ, BBATCH><<<BBATCH, 256, 0, stream>>>(gx1, Whh1, Wih2, bih2, bhh2, gx2);
    k_lstm2h <<<1, 256, 0, stream>>>(gx2, Whh2, dvec, hw, (unsigned int*)d_out);
    (void)out_size;
}

// Round 6
// 419.072 us; speedup vs baseline: 1.4045x; 1.0065x over previous
//
#include <hip/hip_runtime.h>
#include <hip/hip_bf16.h>
#include <cstring>

using bf16 = __hip_bfloat16;
typedef _Float16 h2v __attribute__((ext_vector_type(2)));
typedef _Float16 h8v __attribute__((ext_vector_type(8)));

#if __has_builtin(__builtin_amdgcn_fdot2)
__device__ __forceinline__ float FDOT2(h2v a, h2v b, float c) {
    return __builtin_amdgcn_fdot2(a, b, c, false);
}
#else
__device__ __forceinline__ float FDOT2(h2v a, h2v b, float c) {
    return c + (float)a.x * (float)b.x + (float)a.y * (float)b.y;
}
#endif

// fast sigmoid/tanh: v_exp_f32 + v_rcp_f32, saturate correctly at +-inf, no NaN.
__device__ __forceinline__ float sigm_f(float x) {
    return __builtin_amdgcn_rcpf(1.f + __expf(-x));
}
__device__ __forceinline__ float tanh_f(float x) {
    return 1.f - 2.f * __builtin_amdgcn_rcpf(1.f + __expf(2.f * x));
}

// lane l gets value of lane l^32 (both halves), via VALU permlane32_swap.
__device__ __forceinline__ float xor32_get(float x) {
#if __has_builtin(__builtin_amdgcn_permlane32_swap)
    typedef unsigned uv2 __attribute__((ext_vector_type(2)));
    union { float f; unsigned u; } cv; cv.f = x;
    uv2 r = __builtin_amdgcn_permlane32_swap(cv.u, cv.u, false, false);
    // r[0] = (l<32)? x[l] : x[l-32];  r[1] = (l<32)? x[l+32] : x[l]
    union { unsigned u; float f; } ra, rb; ra.u = r[0]; rb.u = r[1];
    return (ra.f + rb.f) - x;     // = x[l^32] in all lanes (exact: one add/sub pair)
#else
    return __shfl_xor(x, 32);
#endif
}

// cross-half sum: x[l] + x[l^32] for all lanes (r[0]+r[1] identity).
__device__ __forceinline__ float half_sum(float x) {
#if __has_builtin(__builtin_amdgcn_permlane32_swap)
    typedef unsigned uv2 __attribute__((ext_vector_type(2)));
    union { float f; unsigned u; } cv; cv.f = x;
    uv2 r = __builtin_amdgcn_permlane32_swap(cv.u, cv.u, false, false);
    union { unsigned u; float f; } ra, rb; ra.u = r[0]; rb.u = r[1];
    return ra.f + rb.f;
#else
    return x + __shfl_xor(x, 32);
#endif
}

// ---- problem constants ----
constexpr int NH    = 128;    // hidden
constexpr int G4    = 512;    // 4*H gates
constexpr int TSEQ  = 200;
constexpr int BBATCH= 32;
constexpr int NTGT  = 8;

// ---- subgraph caps (Poisson means: |L1|~64, |S1|~72, |L2|~580, |S2|~650) ----
constexpr int LCAP1 = 1024;
constexpr int S1CAP = LCAP1 + NTGT;
constexpr int LCAP2 = 8192;
constexpr int S2CAP = LCAP2 + S1CAP;

// ---- workspace layout (bytes) ----
constexpr size_t algn(size_t x) { return (x + 255) & ~size_t(255); }
constexpr size_t OFF_GX1  = 0;                                            // 6400*512 f32
constexpr size_t OFF_GX2  = algn(OFF_GX1  + 6400ull * G4 * 4);            // 32*512 f32
constexpr size_t OFF_DEG  = algn(OFF_GX2  + 32ull * G4 * 4);              // N i32
constexpr size_t OFF_DINV = algn(OFF_DEG  + 100000ull * 4);               // hw: 1153 f32
constexpr size_t OFF_SL1  = algn(OFF_DINV + 100000ull * 4);               // N i32
constexpr size_t OFF_SL2  = algn(OFF_SL1  + 100000ull * 4);               // N i32
constexpr size_t OFF_CNT  = algn(OFF_SL2  + 100000ull * 4);               // 16 i32
constexpr size_t OFF_L1   = algn(OFF_CNT  + 64);                          // LCAP1 int2
constexpr size_t OFF_S1   = algn(OFF_L1   + (size_t)LCAP1 * 8);           // S1CAP i32
constexpr size_t OFF_L2   = algn(OFF_S1   + (size_t)S1CAP * 4);           // LCAP2 int2
constexpr size_t OFF_S2   = algn(OFF_L2   + (size_t)LCAP2 * 8);           // S2CAP i32
constexpr size_t OFF_XW1  = algn(OFF_S2   + (size_t)S2CAP * 4);           // S2CAP*128 f32
constexpr size_t OFF_H1   = algn(OFF_XW1  + (size_t)S2CAP * NH * 4);      // S1CAP*128 f32
constexpr size_t OFF_XW2  = algn(OFF_H1   + (size_t)S1CAP * NH * 4);      // S1CAP*128 f32
constexpr size_t OFF_DVEC = algn(OFF_XW2  + (size_t)S1CAP * NH * 4);      // 1152 f32
constexpr size_t OFF_H1F  = algn(OFF_DVEC + 1152ull * 4);                 // 32*128 f32 (unused, kept)
constexpr size_t OFF_CACC = algn(OFF_H1F  + 32ull * NH * 4);              // 576 f32 (unused, kept)
constexpr size_t WS_NEEDED = OFF_CACC + 576ull * 4;

// edge_index may be staged as int64 (reference dtype) or int32. If int64,
// odd int32 words are the (all-zero) high halves. cnt[15] = sniffed flag.
__device__ __forceinline__ int edge_at(const int* ei, int E, int is64, int row, int e) {
    return is64 ? ei[(((size_t)row * E) + e) * 2] : ei[((size_t)row * E) + e];
}

__device__ __forceinline__ float dinv_of(const int* deg, int v) {
    return rsqrtf((float)deg[v] + 1.0f);
}

// ============================ GCN subgraph build ============================
__global__ void k_init(const int* ei, int* deg, int* slot1, int* slot2, int* cnt,
                       float* h1, int n, unsigned int* out, unsigned int canary) {
    int i0 = blockIdx.x * 256 + threadIdx.x;
    int gstride = gridDim.x * 256;
    if (i0 < 14) cnt[i0] = 0;
    if (i0 == 15) cnt[15] = (ei[1] == 0 && ei[3] == 0 && ei[5] == 0 && ei[7] == 0) ? 1 : 0;
    if (i0 == 16) out[0] = canary;      // diagnostic; overwritten by k_lstm2h
    for (int i = i0; i < S1CAP * NH; i += gstride) h1[i] = 0.f;
    for (int i = i0; i < n; i += gstride) { deg[i] = 0; slot1[i] = -1; slot2[i] = -1; }
}

__global__ void k_deg_l1(const int* ei, int E, int* deg, int2* l1, int* cnt) {
    int is64 = cnt[15];
    for (int e = blockIdx.x * 256 + threadIdx.x; e < E; e += gridDim.x * 256) {
        int d = edge_at(ei, E, is64, 1, e);
        if ((unsigned)d < 100000u) atomicAdd(&deg[d], 1);
        if (d <= 7000 && d >= 0 && d % 1000 == 0) {          // d in TARGET
            int s = edge_at(ei, E, is64, 0, e);
            int idx = atomicAdd(&cnt[0], 1);
            if (idx < LCAP1) l1[idx] = make_int2(s, d);
        }
    }
}

// S1 set build + S2 seeding (single block)
__global__ void k_s1(const int2* l1, int* cnt, int* slot1, int* s1list,
                     int* slot2, int* s2list) {
    __shared__ int ns1;
    if (threadIdx.x == 0) ns1 = 0;
    __syncthreads();
    int m = min(cnt[0], LCAP1);
    for (int i = threadIdx.x; i < NTGT + m; i += blockDim.x) {
        int v = (i < NTGT) ? i * 1000 : l1[i - NTGT].x;
        if ((unsigned)v >= 100000u) continue;
        int old = atomicCAS(&slot1[v], -1, -2);
        if (old == -1) {
            int idx = atomicAdd(&ns1, 1);
            if (idx < S1CAP) { s1list[idx] = v; atomicExch(&slot1[v], idx); }
        }
    }
    __syncthreads();
    int n1 = min(ns1, S1CAP);
    if (threadIdx.x == 0) cnt[1] = n1;
    for (int i = threadIdx.x; i < n1; i += blockDim.x) {
        int v = s1list[i];
        int old = atomicCAS(&slot2[v], -1, -2);
        if (old == -1) {
            int idx = atomicAdd(&cnt[2], 1);
            if (idx < S2CAP) { s2list[idx] = v; atomicExch(&slot2[v], idx); }
        }
    }
}

__global__ void k_l2(const int* ei, int E, const int* slot1,
                     int2* l2, int* cnt, int* slot2, int* s2list) {
    int is64 = cnt[15];
    for (int e = blockIdx.x * 256 + threadIdx.x; e < E; e += gridDim.x * 256) {
        int d = edge_at(ei, E, is64, 1, e);
        if ((unsigned)d >= 100000u) continue;
        if (slot1[d] >= 0) {
            int s = edge_at(ei, E, is64, 0, e);
            if ((unsigned)s >= 100000u) continue;
            int idx = atomicAdd(&cnt[3], 1);
            if (idx < LCAP2) l2[idx] = make_int2(s, d);
            int old = atomicCAS(&slot2[s], -1, -2);
            if (old == -1) {
                int j = atomicAdd(&cnt[2], 1);
                if (j < S2CAP) { s2list[j] = s; atomicExch(&slot2[s], j); }
            }
        }
    }
}

// ============================ GCN compute (fp32 inputs) ============================

__global__ void k_xw1(const float* x, const float* W, const int* s2list, const int* cnt, float* xw1) {
    int i = blockIdx.x;
    if (i >= min(cnt[2], S2CAP)) return;
    int node = s2list[i];
    __shared__ float xs[NH];
    int c = threadIdx.x;
    xs[c] = x[(size_t)node * NH + c];
    __syncthreads();
    float acc = 0.f;
    #pragma unroll 8
    for (int k = 0; k < NH; k++) acc += xs[k] * W[(size_t)k * NH + c];
    xw1[(size_t)i * NH + c] = acc;
}

__global__ void k_h1scat(const float* xw1, const int2* l2, const int* cnt,
                         const int* slot1, const int* slot2, const int* deg, float* h1) {
    int e = blockIdx.x;
    if (e >= min(cnt[3], LCAP2)) return;
    int2 sd = l2[e];
    int t1 = slot1[sd.y], s2 = slot2[sd.x];
    if (t1 < 0 || t1 >= S1CAP || s2 < 0 || s2 >= S2CAP) return;
    float w = dinv_of(deg, sd.x) * dinv_of(deg, sd.y);
    atomicAdd(&h1[t1 * NH + threadIdx.x],
              xw1[(size_t)s2 * NH + threadIdx.x] * w);
}

// self-loop base term folded in: xs = relu(h1_scatter + xw1[node]*dinv^2 + b1), then @ W2.
__global__ void k_xw2(const float* h1, const float* xw1, const float* W, const float* b1,
                      const int* cnt, const int* s1list, const int* slot2, const int* deg,
                      float* xw2) {
    int i = blockIdx.x;
    if (i >= min(cnt[1], S1CAP)) return;
    __shared__ float xs[NH];
    int c = threadIdx.x;
    int node = s1list[i];
    int s2i = slot2[node];
    if (s2i < 0 || s2i >= S2CAP) s2i = 0;
    float v = dinv_of(deg, node);
    xs[c] = fmaxf(h1[i * NH + c] + xw1[(size_t)s2i * NH + c] * (v * v) + b1[c], 0.f);
    __syncthreads();
    float acc = 0.f;
    #pragma unroll 8
    for (int k = 0; k < NH; k++) acc += xs[k] * W[(size_t)k * NH + c];
    xw2[(size_t)i * NH + c] = acc;
}

__global__ void k_gout(const float* xw2, const int2* l1, const int* cnt,
                       const int* slot1, const int* deg, const float* b2, float* dvec) {
    int t = blockIdx.x;             // 0..7
    int tgt = t * 1000;
    int c = threadIdx.x;
    float vt = dinv_of(deg, tgt);
    int st = slot1[tgt]; if (st < 0 || st >= S1CAP) st = 0;
    float acc = xw2[(size_t)st * NH + c] * vt * vt;
    int m = min(cnt[0], LCAP1);
    for (int e = 0; e < m; e++) {
        int2 sd = l1[e];
        if (sd.y == tgt) {
            int ss = slot1[sd.x];
            if (ss >= 0 && ss < S1CAP)
                acc += xw2[(size_t)ss * NH + c] * dinv_of(deg, sd.x) * vt;
        }
    }
    acc += b2[c];
    dvec[t * NH + c] = fmaxf(acc, 0.f);
}

// ============================ LSTM (fp32 inputs) ============================

// gx1 = data0_rows @ Wih1^T + bias, LDS-tiled GEMM. Blocks >= 800 instead
// compute the head weight-collapse hw = m1w@m2w (1152 f32) + hbias.
__global__ __launch_bounds__(256) void k_gx1hw(const float* data0, const float* Wih,
                                               const float* bih, const float* bhh, float* gx,
                                               const float* m1w, const float* m1b,
                                               const float* m2w, const float* m2b, float* hw) {
    int tid = threadIdx.x;
    if (blockIdx.x >= 800) {
        int hb = blockIdx.x - 800;                // 0..18
        int wv = tid >> 6, ln = tid & 63;
        if (hb < 18) {
            #pragma unroll 4
            for (int rr = 0; rr < 16; rr++) {
                int row = hb * 64 + wv * 16 + rr;
                float s = 0.f;
                #pragma unroll
                for (int j = ln; j < 576; j += 64) s += m1w[(size_t)row * 576 + j] * m2w[j];
                #pragma unroll
                for (int off = 32; off > 0; off >>= 1) s += __shfl_down(s, off, 64);
                if (ln == 0) hw[row] = s;
            }
        } else if (wv == 0) {                     // hbias = m1b@m2w + m2b
            float s = 0.f;
            for (int j = ln; j < 576; j += 64) s += m1b[j] * m2w[j];
            #pragma unroll
            for (int off = 32; off > 0; off >>= 1) s += __shfl_down(s, off, 64);
            if (ln == 0) hw[1152] = s + m2b[0];
        }
        return;
    }
    constexpr int LDP = 68;                       // pad 64->68 breaks bank conflicts
    __shared__ float As[64 * LDP];                // rows x k
    __shared__ float Bs[64 * LDP];                // gates x k
    int rb = blockIdx.x >> 3;                     // 0..99  row block
    int gb = blockIdx.x & 7;                      // 0..7   gate block
    int r0 = rb * 64, g0 = gb * 64;
    for (int i = tid; i < 64 * 64; i += 256) {
        int rr = i >> 6, k = i & 63;
        int r = r0 + rr, b = r & 31, t = r >> 5;
        As[rr * LDP + k] = data0[((size_t)b * TSEQ + t) * 64 + k];
        Bs[rr * LDP + k] = Wih[(size_t)(g0 + rr) * 64 + k];
    }
    __syncthreads();
    int tr = (tid & 15) * 4;                      // 4 rows
    int tg = (tid >> 4) * 4;                      // 4 gates
    float acc[4][4] = {};
    #pragma unroll
    for (int k4 = 0; k4 < 16; k4++) {
        float4 a0 = *(const float4*)&As[(tr + 0) * LDP + k4 * 4];
        float4 a1 = *(const float4*)&As[(tr + 1) * LDP + k4 * 4];
        float4 a2 = *(const float4*)&As[(tr + 2) * LDP + k4 * 4];
        float4 a3 = *(const float4*)&As[(tr + 3) * LDP + k4 * 4];
        float4 b0 = *(const float4*)&Bs[(tg + 0) * LDP + k4 * 4];
        float4 b1 = *(const float4*)&Bs[(tg + 1) * LDP + k4 * 4];
        float4 b2 = *(const float4*)&Bs[(tg + 2) * LDP + k4 * 4];
        float4 b3 = *(const float4*)&Bs[(tg + 3) * LDP + k4 * 4];
        const float4 av[4] = {a0, a1, a2, a3};
        const float4 bv[4] = {b0, b1, b2, b3};
        #pragma unroll
        for (int i = 0; i < 4; i++)
            #pragma unroll
            for (int j = 0; j < 4; j++)
                acc[i][j] += av[i].x * bv[j].x + av[i].y * bv[j].y
                           + av[i].z * bv[j].z + av[i].w * bv[j].w;
    }
    float bias[4];
    #pragma unroll
    for (int j = 0; j < 4; j++) bias[j] = bih[g0 + tg + j] + bhh[g0 + tg + j];
    #pragma unroll
    for (int i = 0; i < 4; i++) {
        size_t row = (size_t)(r0 + tr + i) * G4 + g0 + tg;
        #pragma unroll
        for (int j = 0; j < 4; j++) gx[row + j] = acc[i][j] + bias[j];
    }
}

// R14 half-k recurrence. Model (validated R0/R1/R3): step time is dominated
// by LDS RETURN bandwidth — each lane must RECEIVE h; broadcast doesn't help.
// Old: every lane read all 256B of h (16 b128) -> 64KB/CU/step ~ 770 cyc.
// New: lane l sums k in [ (l>=32)*64, +64 ) for ALL FOUR gate rows of unit
// j = w*32+(l&31): reads only 8 b128 (128B) -> ~385 cyc. Weight footprint
// UNCHANGED (4 rows x 64 f16 = 128 h2v; R4 lesson: 256 h2v spills).
// Halves combine via permlane32_swap (VALU, off the LDS pipe): r[0]+r[1]
// = x[l]+x[l^32] in all lanes. Then the proven transc split: half0 does
// sigm(i),tanh(g); half1 sigm(f),sigm(o); cross s/tg; half0 updates c,h.
template<int T, int NB>
__global__ __launch_bounds__(256, 1) void k_lstm1g(const float* gx, const float* Whh,
                                                   const float* Wih2, const float* bih2,
                                                   const float* bhh2, float* gx2) {
    int b = blockIdx.x;
    int tid = threadIdx.x;
    int w = tid >> 6, l = tid & 63;
    int j = w * 32 + (l & 31);                    // hidden unit
    int hf = l >> 5;                              // which k-half this lane sums
    int k0 = hf * 64;
    __shared__ __align__(16) _Float16 hbuf[2][NH];
    __shared__ float hfin[NH];
    h2v wi[32], wf[32], wg[32], wo[32];           // 4 rows x 64 k = 128 VGPRs
    #pragma unroll
    for (int k = 0; k < 64; k += 4) {
        float4 a;
        a = *(const float4*)&Whh[(size_t)j * NH + k0 + k];
        wi[k / 2] = h2v{(_Float16)a.x, (_Float16)a.y};
        wi[k / 2 + 1] = h2v{(_Float16)a.z, (_Float16)a.w};
        a = *(const float4*)&Whh[(size_t)(j + NH) * NH + k0 + k];
        wf[k / 2] = h2v{(_Float16)a.x, (_Float16)a.y};
        wf[k / 2 + 1] = h2v{(_Float16)a.z, (_Float16)a.w};
        a = *(const float4*)&Whh[(size_t)(j + 2 * NH) * NH + k0 + k];
        wg[k / 2] = h2v{(_Float16)a.x, (_Float16)a.y};
        wg[k / 2 + 1] = h2v{(_Float16)a.z, (_Float16)a.w};
        a = *(const float4*)&Whh[(size_t)(j + 3 * NH) * NH + k0 + k];
        wo[k / 2] = h2v{(_Float16)a.x, (_Float16)a.y};
        wo[k / 2 + 1] = h2v{(_Float16)a.z, (_Float16)a.w};
    }
    if (tid < NH) { hbuf[0][tid] = (_Float16)0.f; hbuf[1][tid] = (_Float16)0.f; }
    float c = 0.f, hout = 0.f;
    const float* gp0 = &gx[(size_t)b * G4];
    float nx0 = gp0[j], nx1 = gp0[j + NH], nx2 = gp0[j + 2 * NH], nx3 = gp0[j + 3 * NH];
    __syncthreads();
    for (int t = 0; t < T; t++) {
        const h8v* hv8 = (const h8v*)&hbuf[t & 1][k0];      // 8 b128: this half of h
        float a0 = nx0, a1 = nx1, a2 = nx2, a3 = nx3;
        int tn = (t + 1 < T) ? (t + 1) : t;
        const float* gp = &gx[((size_t)tn * NB + b) * G4];  // prefetch next step
        nx0 = gp[j]; nx1 = gp[j + NH]; nx2 = gp[j + 2 * NH]; nx3 = gp[j + 3 * NH];
        float pi = 0.f, qi = 0.f, pf = 0.f, qf = 0.f;
        float pg = 0.f, qg = 0.f, po = 0.f, qo = 0.f;
        #pragma unroll
        for (int m = 0; m < 8; m++) {                       // 128 fdot2 total
            h8v h8 = hv8[m];
            h2v ha = __builtin_shufflevector(h8, h8, 0, 1);
            h2v hb = __builtin_shufflevector(h8, h8, 2, 3);
            h2v hc = __builtin_shufflevector(h8, h8, 4, 5);
            h2v hd = __builtin_shufflevector(h8, h8, 6, 7);
            pi = FDOT2(wi[4 * m],     ha, pi);
            qi = FDOT2(wi[4 * m + 1], hb, qi);
            pi = FDOT2(wi[4 * m + 2], hc, pi);
            qi = FDOT2(wi[4 * m + 3], hd, qi);
            pf = FDOT2(wf[4 * m],     ha, pf);
            qf = FDOT2(wf[4 * m + 1], hb, qf);
            pf = FDOT2(wf[4 * m + 2], hc, pf);
            qf = FDOT2(wf[4 * m + 3], hd, qf);
            pg = FDOT2(wg[4 * m],     ha, pg);
            qg = FDOT2(wg[4 * m + 1], hb, qg);
            pg = FDOT2(wg[4 * m + 2], hc, pg);
            qg = FDOT2(wg[4 * m + 3], hd, qg);
            po = FDOT2(wo[4 * m],     ha, po);
            qo = FDOT2(wo[4 * m + 1], hb, qo);
            po = FDOT2(wo[4 * m + 2], hc, po);
            qo = FDOT2(wo[4 * m + 3], hd, qo);
        }
        float gi = a0 + half_sum(pi + qi);                  // full dots, all lanes
        float gf = a1 + half_sum(pf + qf);
        float gg = a2 + half_sum(pg + qg);
        float go = a3 + half_sum(po + qo);
        float s  = sigm_f(hf ? gf : gi);                    // sigm(i) | sigm(f)
        float tg = hf ? sigm_f(go) : tanh_f(gg);            // tanh(g) | sigm(o)
        float u  = s * tg;                                  // half0: sigm(i)*tanh(g)
        float fv = xor32_get(s);                            // half0 gets sigm(f)
        float ov = xor32_get(tg);                           // half0 gets sigm(o)
        if (hf == 0) {
            c = fv * c + u;
            hout = ov * tanh_f(c);
            hbuf[(t + 1) & 1][j] = (_Float16)hout;          // write other buffer
        }
        __syncthreads();                                    // single barrier/step
    }
    if (hf == 0) hfin[j] = hout;                            // exact f32 h for gx2
    __syncthreads();
    // ---- folded k_gx2 (float4-vectorized): gx2[b][g] = hfin.Wih2[g]+biases ----
    int g0 = tid, g1 = tid + 256;
    float a0 = bih2[g0] + bhh2[g0];
    float a1 = bih2[g1] + bhh2[g1];
    const float4* w0p = (const float4*)&Wih2[(size_t)g0 * NH];
    const float4* w1p = (const float4*)&Wih2[(size_t)g1 * NH];
    const float4* hp  = (const float4*)hfin;
    #pragma unroll 8
    for (int k4 = 0; k4 < NH / 4; k4++) {
        float4 h4 = hp[k4];
        float4 wa = w0p[k4];
        float4 wb = w1p[k4];
        a0 += wa.x * h4.x + wa.y * h4.y + wa.z * h4.z + wa.w * h4.w;
        a1 += wb.x * h4.x + wb.y * h4.y + wb.z * h4.z + wb.w * h4.w;
    }
    gx2[(size_t)b * G4 + g0] = a0;
    gx2[(size_t)b * G4 + g1] = a1;
}

// lstm2 (T=32, NB=1, 1 block, half-k structure) + folded head epilogue:
// out = dvec[0:1024].hw[0:1024] + h2.hw[1024:1152] + hw[1152]  (bf16 dual store)
__global__ __launch_bounds__(256, 1) void k_lstm2h(const float* gx, const float* Whh,
                                                   const float* dvec, const float* hw,
                                                   unsigned int* out) {
    constexpr int T = BBATCH;                     // 32 steps
    int tid = threadIdx.x;
    int w = tid >> 6, l = tid & 63;
    int j = w * 32 + (l & 31);
    int hf = l >> 5;
    int k0 = hf * 64;
    __shared__ __align__(16) _Float16 hbuf[2][NH];
    __shared__ float harr[NH];
    __shared__ float red[4];
    h2v wi[32], wf[32], wg[32], wo[32];
    #pragma unroll
    for (int k = 0; k < 64; k += 4) {
        float4 a;
        a = *(const float4*)&Whh[(size_t)j * NH + k0 + k];
        wi[k / 2] = h2v{(_Float16)a.x, (_Float16)a.y};
        wi[k / 2 + 1] = h2v{(_Float16)a.z, (_Float16)a.w};
        a = *(const float4*)&Whh[(size_t)(j + NH) * NH + k0 + k];
        wf[k / 2] = h2v{(_Float16)a.x, (_Float16)a.y};
        wf[k / 2 + 1] = h2v{(_Float16)a.z, (_Float16)a.w};
        a = *(const float4*)&Whh[(size_t)(j + 2 * NH) * NH + k0 + k];
        wg[k / 2] = h2v{(_Float16)a.x, (_Float16)a.y};
        wg[k / 2 + 1] = h2v{(_Float16)a.z, (_Float16)a.w};
        a = *(const float4*)&Whh[(size_t)(j + 3 * NH) * NH + k0 + k];
        wo[k / 2] = h2v{(_Float16)a.x, (_Float16)a.y};
        wo[k / 2 + 1] = h2v{(_Float16)a.z, (_Float16)a.w};
    }
    if (tid < NH) { hbuf[0][tid] = (_Float16)0.f; hbuf[1][tid] = (_Float16)0.f; }
    float c = 0.f, hout = 0.f;
    float nx0 = gx[j], nx1 = gx[j + NH], nx2 = gx[j + 2 * NH], nx3 = gx[j + 3 * NH];
    __syncthreads();
    for (int t = 0; t < T; t++) {
        const h8v* hv8 = (const h8v*)&hbuf[t & 1][k0];
        float a0 = nx0, a1 = nx1, a2 = nx2, a3 = nx3;
        int tn = (t + 1 < T) ? (t + 1) : t;
        const float* gp = &gx[(size_t)tn * G4];
        nx0 = gp[j]; nx1 = gp[j + NH]; nx2 = gp[j + 2 * NH]; nx3 = gp[j + 3 * NH];
        float pi = 0.f, qi = 0.f, pf = 0.f, qf = 0.f;
        float pg = 0.f, qg = 0.f, po = 0.f, qo = 0.f;
        #pragma unroll
        for (int m = 0; m < 8; m++) {
            h8v h8 = hv8[m];
            h2v ha = __builtin_shufflevector(h8, h8, 0, 1);
            h2v hb = __builtin_shufflevector(h8, h8, 2, 3);
            h2v hc = __builtin_shufflevector(h8, h8, 4, 5);
            h2v hd = __builtin_shufflevector(h8, h8, 6, 7);
            pi = FDOT2(wi[4 * m],     ha, pi);
            qi = FDOT2(wi[4 * m + 1], hb, qi);
            pi = FDOT2(wi[4 * m + 2], hc, pi);
            qi = FDOT2(wi[4 * m + 3], hd, qi);
            pf = FDOT2(wf[4 * m],     ha, pf);
            qf = FDOT2(wf[4 * m + 1], hb, qf);
            pf = FDOT2(wf[4 * m + 2], hc, pf);
            qf = FDOT2(wf[4 * m + 3], hd, qf);
            pg = FDOT2(wg[4 * m],     ha, pg);
            qg = FDOT2(wg[4 * m + 1], hb, qg);
            pg = FDOT2(wg[4 * m + 2], hc, pg);
            qg = FDOT2(wg[4 * m + 3], hd, qg);
            po = FDOT2(wo[4 * m],     ha, po);
            qo = FDOT2(wo[4 * m + 1], hb, qo);
            po = FDOT2(wo[4 * m + 2], hc, po);
            qo = FDOT2(wo[4 * m + 3], hd, qo);
        }
        float gi = a0 + half_sum(pi + qi);
        float gf = a1 + half_sum(pf + qf);
        float gg = a2 + half_sum(pg + qg);
        float go = a3 + half_sum(po + qo);
        float s  = sigm_f(hf ? gf : gi);
        float tg = hf ? sigm_f(go) : tanh_f(gg);
        float u  = s * tg;
        float fv = xor32_get(s);
        float ov = xor32_get(tg);
        if (hf == 0) {
            c = fv * c + u;
            hout = ov * tanh_f(c);
            hbuf[(t + 1) & 1][j] = (_Float16)hout;
        }
        __syncthreads();
    }
    if (hf == 0) harr[j] = hout;
    __syncthreads();
    // ---- folded head: final 1152-dot against collapsed weights hw ----
    float s = 0.f;
    for (int i = tid; i < 1024; i += 256) s += dvec[i] * hw[i];
    if (tid < NH) s += harr[tid] * hw[1024 + tid];
    #pragma unroll
    for (int off = 32; off > 0; off >>= 1) s += __shfl_down(s, off, 64);
    if ((tid & 63) == 0) red[tid >> 6] = s;
    __syncthreads();
    if (tid == 0) {
        float tot = red[0] + red[1] + red[2] + red[3] + hw[1152];
        bf16 hb = __float2bfloat16(tot);
        unsigned short u;
        memcpy(&u, &hb, 2);
        out[0] = ((unsigned int)u << 16) | u;
    }
}

// ============================ launcher ============================

extern "C" void kernel_launch(void* const* d_in, const int* in_sizes, int n_in,
                              void* d_out, int out_size, void* d_ws, size_t ws_size,
                              hipStream_t stream) {
    const float* data0 = (const float*)d_in[0];
    const float* data1 = (const float*)d_in[1];
    const int*   ei    = (const int*)d_in[2];
    const float* W1    = (const float*)d_in[3];
    const float* b1    = (const float*)d_in[4];
    const float* W2    = (const float*)d_in[5];
    const float* b2    = (const float*)d_in[6];
    const float* Wih1  = (const float*)d_in[7];
    const float* Whh1  = (const float*)d_in[8];
    const float* bih1  = (const float*)d_in[9];
    const float* bhh1  = (const float*)d_in[10];
    const float* Wih2  = (const float*)d_in[11];
    const float* Whh2  = (const float*)d_in[12];
    const float* bih2  = (const float*)d_in[13];
    const float* bhh2  = (const float*)d_in[14];
    const float* m1w   = (const float*)d_in[15];
    const float* m1b   = (const float*)d_in[16];
    const float* m2w   = (const float*)d_in[17];
    const float* m2b   = (const float*)d_in[18];

    const int n = in_sizes[1] / NH;       // 100000
    const int E = in_sizes[2] / 2;        // 800000 (elements; int width sniffed on device)

    char* ws = (char*)d_ws;
    float* gx1   = (float*)(ws + OFF_GX1);
    float* gx2   = (float*)(ws + OFF_GX2);
    int*   deg   = (int*)  (ws + OFF_DEG);
    float* hw    = (float*)(ws + OFF_DINV);   // 1153 f32, reuses dead region
    int*   slot1 = (int*)  (ws + OFF_SL1);
    int*   slot2 = (int*)  (ws + OFF_SL2);
    int*   cnt   = (int*)  (ws + OFF_CNT);
    int2*  l1    = (int2*) (ws + OFF_L1);
    int*   s1l   = (int*)  (ws + OFF_S1);
    int2*  l2    = (int2*) (ws + OFF_L2);
    int*   s2l   = (int*)  (ws + OFF_S2);
    float* xw1   = (float*)(ws + OFF_XW1);
    float* h1    = (float*)(ws + OFF_H1);
    float* xw2   = (float*)(ws + OFF_XW2);
    float* dvec  = (float*)(ws + OFF_DVEC);

    // diagnostic canary bits (written by k_init, overwritten by k_lstm2h)
    float v = 1.0f + (ws_size < WS_NEEDED ? 1.0f : 0.0f) + (n_in != 19 ? 2.0f : 0.0f);
    unsigned int fb; memcpy(&fb, &v, 4);
    unsigned int hi = fb >> 16;
    unsigned int canary_bits = (hi << 16) | hi;

    int nb = (n + 255) / 256;
    int eb = (E + 255) / 256;

    // subgraph build
    k_init   <<<nb, 256, 0, stream>>>(ei, deg, slot1, slot2, cnt, h1, n,
                                      (unsigned int*)d_out, canary_bits);
    k_deg_l1 <<<eb, 256, 0, stream>>>(ei, E, deg, l1, cnt);
    k_s1     <<<1, 256, 0, stream>>>(l1, cnt, slot1, s1l, slot2, s2l);
    k_l2     <<<eb, 256, 0, stream>>>(ei, E, slot1, l2, cnt, slot2, s2l);
    // GCN compute on active subgraph
    k_xw1    <<<S2CAP, NH, 0, stream>>>(data1, W1, s2l, cnt, xw1);
    k_h1scat <<<LCAP2, NH, 0, stream>>>(xw1, l2, cnt, slot1, slot2, deg, h1);
    k_xw2    <<<S1CAP, NH, 0, stream>>>(h1, xw1, W2, b1, cnt, s1l, slot2, deg, xw2);
    k_gout   <<<NTGT, NH, 0, stream>>>(xw2, l1, cnt, slot1, deg, b2, dvec);
    // LSTM path (+ head weight-collapse piggybacked on gx1's dispatch)
    k_gx1hw  <<<819, 256, 0, stream>>>(data0, Wih1, bih1, bhh1, gx1,
                                       m1w, m1b, m2w, m2b, hw);
    k_lstm1g<TSEQ, BBATCH><<<BBATCH, 256, 0, stream>>>(gx1, Whh1, Wih2, bih2, bhh2, gx2);
    k_lstm2h <<<1, 256, 0, stream>>>(gx2, Whh2, dvec, hw, (unsigned int*)d_out);
    (void)out_size;
}